// Round 2
// baseline (226.919 us; speedup 1.0000x reference)
//
#include <hip/hip_runtime.h>
#include <cstdint>
#include <cstddef>

// Problem constants (from reference): B=16, S=4096, C=512, A=0.5
#define PB 16
#define PS 4096
#define PC 512

// ---------------------------------------------------------------------------
// K1 (R10): register-direct streaming pass, de-atomicized colsum.
// 1024 blocks x 256 thr; each wave owns 16 rows (4 chunks x 4 rows), issues
// 8 float4 loads per chunk (8 KB in flight/wave). Lane l owns cols
// {4l..4l+3, 256+4l..256+4l+3} in EVERY row -> column partials accumulate in
// registers across all 16 rows; one LDS combine + plain (non-atomic) 2 KB
// partial store per block. Replaces R5's 2M device-scope atomicAdds
// (256-way same-address contention) with 512K plain coalesced stores.
// grid=1024 = 4 blocks/CU -> whole grid co-resident.
// NOTE (R8): plain loads, NOT nontemporal (harness restore makes pred L3-hot).
// NOTE (R6): no __threadfence; kernel boundary orders the partial stores.
// NOTE (R4): no min-waves launch bound — VGPR squeeze serializes loads.
// ---------------------------------------------------------------------------
__global__ __launch_bounds__(256) void k1_rows(const float* __restrict__ pred,
                                               int* __restrict__ am,
                                               float* __restrict__ lse,
                                               float* __restrict__ partial) {
    const int t = threadIdx.x, w = t >> 6, l = t & 63;
    const int blockRow = blockIdx.x * 64;          // 64 consecutive rows/block
    const int b = blockRow >> 12;                  // PS = 4096 (64 | 4096)
    const int waveRow = blockRow + w * 16;         // 16 rows per wave

    float cs[8] = {0.f, 0.f, 0.f, 0.f, 0.f, 0.f, 0.f, 0.f};

    #pragma unroll 2
    for (int ch = 0; ch < 4; ++ch) {
        const int rowBase = waveRow + ch * 4;
        const float* base = pred + (size_t)rowBase * PC + 4 * l;

        float4 va[4], vb[4];
        #pragma unroll
        for (int r = 0; r < 4; ++r) {
            va[r] = *(const float4*)(base + r * PC);
            vb[r] = *(const float4*)(base + r * PC + 256);
        }

        // lane-local argmax over 8 elements per row (earliest index wins)
        float mv[4]; int mi[4];
        #pragma unroll
        for (int r = 0; r < 4; ++r) {
            float m = va[r].x; int i0 = 4 * l;
            if (va[r].y > m) { m = va[r].y; i0 = 4 * l + 1; }
            if (va[r].z > m) { m = va[r].z; i0 = 4 * l + 2; }
            if (va[r].w > m) { m = va[r].w; i0 = 4 * l + 3; }
            if (vb[r].x > m) { m = vb[r].x; i0 = 256 + 4 * l; }
            if (vb[r].y > m) { m = vb[r].y; i0 = 256 + 4 * l + 1; }
            if (vb[r].z > m) { m = vb[r].z; i0 = 256 + 4 * l + 2; }
            if (vb[r].w > m) { m = vb[r].w; i0 = 256 + 4 * l + 3; }
            mv[r] = m; mi[r] = i0;
        }

        // 4 interleaved butterflies: (max, min-index-on-tie) is assoc+comm
        #pragma unroll
        for (int off = 1; off < 64; off <<= 1) {
            #pragma unroll
            for (int r = 0; r < 4; ++r) {
                float ov = __shfl_xor(mv[r], off, 64);
                int   oi = __shfl_xor(mi[r], off, 64);
                if (ov > mv[r] || (ov == mv[r] && oi < mi[r])) { mv[r] = ov; mi[r] = oi; }
            }
        }

        // exp sums (mv[r] is now the true row max)
        float ss[4];
        #pragma unroll
        for (int r = 0; r < 4; ++r) {
            ss[r] = __expf(va[r].x - mv[r]) + __expf(va[r].y - mv[r])
                  + __expf(va[r].z - mv[r]) + __expf(va[r].w - mv[r])
                  + __expf(vb[r].x - mv[r]) + __expf(vb[r].y - mv[r])
                  + __expf(vb[r].z - mv[r]) + __expf(vb[r].w - mv[r]);
        }
        #pragma unroll
        for (int off = 1; off < 64; off <<= 1) {
            #pragma unroll
            for (int r = 0; r < 4; ++r) ss[r] += __shfl_xor(ss[r], off, 64);
        }

        if (l == 0) {
            float l0 = mv[0] + __logf(ss[0]);
            float l1 = mv[1] + __logf(ss[1]);
            float l2 = mv[2] + __logf(ss[2]);
            float l3 = mv[3] + __logf(ss[3]);
            *(float4*)(lse + rowBase) = make_float4(l0, l1, l2, l3);
            *(int4*)(am + rowBase) = make_int4(mi[0], mi[1], mi[2], mi[3]);
        }

        // accumulate column partials in registers (same cols every chunk)
        cs[0] += va[0].x + va[1].x + va[2].x + va[3].x;
        cs[1] += va[0].y + va[1].y + va[2].y + va[3].y;
        cs[2] += va[0].z + va[1].z + va[2].z + va[3].z;
        cs[3] += va[0].w + va[1].w + va[2].w + va[3].w;
        cs[4] += vb[0].x + vb[1].x + vb[2].x + vb[3].x;
        cs[5] += vb[0].y + vb[1].y + vb[2].y + vb[3].y;
        cs[6] += vb[0].z + vb[1].z + vb[2].z + vb[3].z;
        cs[7] += vb[0].w + vb[1].w + vb[2].w + vb[3].w;
    }

    __shared__ float lds[4][PC];   // 8 KB
    lds[w][4 * l + 0] = cs[0]; lds[w][4 * l + 1] = cs[1];
    lds[w][4 * l + 2] = cs[2]; lds[w][4 * l + 3] = cs[3];
    lds[w][256 + 4 * l + 0] = cs[4]; lds[w][256 + 4 * l + 1] = cs[5];
    lds[w][256 + 4 * l + 2] = cs[6]; lds[w][256 + 4 * l + 3] = cs[7];
    __syncthreads();
    float* pout = partial + (size_t)blockIdx.x * PC;
    for (int c = t; c < PC; c += 256) {
        pout[c] = lds[0][c] + lds[1][c] + lds[2][c] + lds[3][c];  // plain store
    }
}

// ---------------------------------------------------------------------------
// K_TAIL: one block (1024 threads) per batch. New in R10: reduces the 64
// per-block column partials of its batch into LDS colS (64 coalesced 2KB
// rounds, overlapped with the histogram phase) — colsum atomics are gone.
// Rest unchanged: vectorized pass-1, LDS histogram, shfl wave-scan, register
// scatter, per-class mode/eq/ne/val, block reduce -> acc atomics, finalize.
// ---------------------------------------------------------------------------
__global__ __launch_bounds__(1024) void k_tail(const float* __restrict__ pred,
                                               const int* __restrict__ target,
                                               const int* __restrict__ am,
                                               const float* __restrict__ lse,
                                               const float* __restrict__ partial,
                                               float* __restrict__ acc,
                                               int* __restrict__ done,
                                               float* __restrict__ out) {
    __shared__ float ldsLse[PS];   // 16 KB
    __shared__ int   sbucket[PS];  // 16 KB: s | am<<12
    __shared__ int   cnt[PC];      // 2 KB
    __shared__ int   offsA[PC];    // 2 KB
    __shared__ int   cur[PC];      // 2 KB
    __shared__ float colS[PC];     // 2 KB: reduced column sums for this batch
    __shared__ float redL[16];
    __shared__ int   redS[8];
    __shared__ float redv[16], redk[16];

    const int b = blockIdx.x, t = threadIdx.x, w = t >> 6, l = t & 63;
    if (t < PC) cnt[t] = 0;
    __syncthreads();

    // column-partial reduction: thread t<512 owns column t, sums 64 blocks.
    // Issued early so the 64 coalesced loads overlap the histogram below;
    // colS is not read until the eval phase (3 barriers later).
    if (t < PC) {
        const float* pp = partial + (size_t)(b * 64) * PC + t;
        float s = 0.0f;
        #pragma unroll 8
        for (int g = 0; g < 64; ++g) s += pp[(size_t)g * PC];
        colS[t] = s;
    }

    // pass 1: 4 consecutive elements per thread, fully vectorized
    const int4*   tg4p = (const int4*)(target + (b << 12));
    const int4*   am4p = (const int4*)(am + (b << 12));
    const float4* ls4p = (const float4*)(lse + (b << 12));
    int4 tg4 = tg4p[t];
    int4 am4 = am4p[t];
    float4 ls4 = ls4p[t];
    ((float4*)ldsLse)[t] = ls4;
    atomicAdd(&cnt[tg4.x], 1);
    atomicAdd(&cnt[tg4.y], 1);
    atomicAdd(&cnt[tg4.z], 1);
    atomicAdd(&cnt[tg4.w], 1);
    float lacc = ls4.x + ls4.y + ls4.z + ls4.w;
    #pragma unroll
    for (int off = 1; off < 64; off <<= 1) lacc += __shfl_xor(lacc, off, 64);
    if (l == 0) redL[w] = lacc;
    __syncthreads();                       // cnt, ldsLse, redL, colS ready
    float Ls = 0.0f;
    #pragma unroll
    for (int j = 0; j < 16; ++j) Ls += redL[j];

    // exclusive scan over 512 classes: threads 0..511 (waves 0..7), shfl scan
    int x = 0, incl = 0;
    if (t < PC) {
        x = cnt[t];
        incl = x;
        #pragma unroll
        for (int off = 1; off < 64; off <<= 1) {
            int v = __shfl_up(incl, off, 64);
            if (l >= off) incl += v;
        }
        if (l == 63) redS[w] = incl;
    }
    __syncthreads();
    if (t < PC) {
        int woff = 0;
        #pragma unroll
        for (int j = 0; j < 8; ++j) woff += (j < w) ? redS[j] : 0;
        int excl = incl + woff - x;
        offsA[t] = excl;
        cur[t] = excl;
    }
    __syncthreads();

    // scatter from registers (elements 4t..4t+3)
    {
        int pos;
        pos = atomicAdd(&cur[tg4.x], 1); sbucket[pos] = (4 * t + 0) | (am4.x << 12);
        pos = atomicAdd(&cur[tg4.y], 1); sbucket[pos] = (4 * t + 1) | (am4.y << 12);
        pos = atomicAdd(&cur[tg4.z], 1); sbucket[pos] = (4 * t + 2) | (am4.z << 12);
        pos = atomicAdd(&cur[tg4.w], 1); sbucket[pos] = (4 * t + 3) | (am4.w << 12);
    }
    __syncthreads();

    // per-class eval: thread t < 512 owns class t
    float val = 0.0f; int keep = 0;
    if (t < PC && x > 0) {
        int k = x, start = offsA[t];
        int bc = 0, bvv = 0;               // mode; tie -> smallest class
        for (int i = 0; i < k; ++i) {
            int v = sbucket[start + i] >> 12;
            int c = 0;
            for (int j = 0; j < k; ++j) c += ((sbucket[start + j] >> 12) == v) ? 1 : 0;
            if (c > bc || (c == bc && v < bvv)) { bc = c; bvv = v; }
        }
        int m = bvv;
        float lseSum = 0.0f, ep0 = 0.0f, ep1 = 0.0f;
        const float* pb = pred + (size_t)(b << 12) * PC + m;
        int i = 0;
        for (; i + 1 < k; i += 2) {        // 2-way unroll: 2 loads in flight
            int s0 = sbucket[start + i] & (PS - 1);
            int s1 = sbucket[start + i + 1] & (PS - 1);
            lseSum += ldsLse[s0] + ldsLse[s1];
            ep0 += pb[(size_t)s0 * PC];
            ep1 += pb[(size_t)s1 * PC];
        }
        if (i < k) {
            int s0 = sbucket[start + i] & (PS - 1);
            lseSum += ldsLse[s0];
            ep0 += pb[(size_t)s0 * PC];
        }
        float eq_sum = lseSum - (ep0 + ep1);
        float ne_sum = (Ls - colS[m]) - eq_sum;
        float nf = (float)k;
        float eq_loss = eq_sum / fmaxf(nf, 1.0f);
        float ne_mean = ne_sum / fmaxf((float)PS - nf, 1.0f);
        float ne_loss = 1.0f / ((ne_mean != 0.0f) ? ne_mean : 1.0f);
        val = 0.5f * eq_loss + 0.5f * ne_loss;
        keep = (val != 0.0f) ? 1 : 0;
    }

    float vs = keep ? val : 0.0f;
    float ks = (float)keep;
    #pragma unroll
    for (int off = 1; off < 64; off <<= 1) {
        vs += __shfl_xor(vs, off, 64);
        ks += __shfl_xor(ks, off, 64);
    }
    if (l == 0) { redv[w] = vs; redk[w] = ks; }
    __syncthreads();
    if (t == 0) {
        float sv = 0.0f, sk = 0.0f;
        #pragma unroll
        for (int j = 0; j < 16; ++j) { sv += redv[j]; sk += redk[j]; }
        atomicAdd(&acc[0], sv);
        atomicAdd(&acc[1], sk);
        __threadfence();
        int d = atomicAdd(done, 1);
        if (d == PB - 1) {                 // last batch-block finalizes
            __threadfence();
            float a0 = atomicAdd(&acc[0], 0.0f);
            float a1 = atomicAdd(&acc[1], 0.0f);
            out[0] = a0 / fmaxf(a1, 1.0f);
        }
    }
}

extern "C" void kernel_launch(void* const* d_in, const int* in_sizes, int n_in,
                              void* d_out, int out_size, void* d_ws, size_t ws_size,
                              hipStream_t stream) {
    const float* pred = (const float*)d_in[0];   // (B,S,C) f32
    const int* target = (const int*)d_in[1];     // (B,S) int
    float* out = (float*)d_out;

    char* w = (char*)d_ws;
    int*   am      = (int*)(w + 0);          // B*S ints   = 256 KiB
    float* lse     = (float*)(w + 262144);   // B*S floats = 256 KiB
    float* partial = (float*)(w + 524288);   // 1024*512 floats = 2 MiB (fully written by k1)
    float* acc     = (float*)(w + 2621440);  // 2 floats  <- memset 0
    int*   done    = (int*)(w + 2621448);    // 1 int     <- memset 0

    (void)hipMemsetAsync(w + 2621440, 0, 12, stream);
    k1_rows<<<(PB * PS) / 64, 256, 0, stream>>>(pred, am, lse, partial);
    k_tail<<<PB, 1024, 0, stream>>>(pred, target, am, lse, partial, acc, done, out);
}

// Round 4
// 224.368 us; speedup vs baseline: 1.0114x; 1.0114x over previous
//
#include <hip/hip_runtime.h>
#include <cstdint>
#include <cstddef>

// Problem constants (from reference): B=16, S=4096, C=512, A=0.5
#define PB 16
#define PS 4096
#define PC 512

// ---------------------------------------------------------------------------
// K1: register-direct streaming pass (R5/R1 structure — measured fastest,
// 220 µs total; R2's 64-row/1024-block variant regressed +7 µs: only ~4
// waves/SIMD exposed load latency). 4096 blocks x 256 thr; each wave owns 4
// rows, issues all 8 float4 loads up front. 4 interleaved butterfly chains.
// Atomic colsum (R2 proved de-atomicizing is NOT a win — 2M memside atomics
// are cheap). Plain loads (NOT nontemporal — R8). No threadfence (R6: wbl2
// per block serialized = 709 us). No min-waves bound (R4).
// ---------------------------------------------------------------------------
__global__ __launch_bounds__(256) void k1_rows(const float* __restrict__ pred,
                                               int* __restrict__ am,
                                               float* __restrict__ lse,
                                               float* __restrict__ colsum) {
    const int t = threadIdx.x, w = t >> 6, l = t & 63;
    const int rowBase = blockIdx.x * 16 + w * 4;   // 4 consecutive rows per wave
    const int b = rowBase >> 12;                   // PS = 4096
    const float* base = pred + (size_t)rowBase * PC + 4 * l;

    float4 va[4], vb[4];
    #pragma unroll
    for (int r = 0; r < 4; ++r) {
        va[r] = *(const float4*)(base + r * PC);
        vb[r] = *(const float4*)(base + r * PC + 256);
    }

    // lane-local argmax over 8 elements per row (earliest index wins: strict >)
    float mv[4]; int mi[4];
    #pragma unroll
    for (int r = 0; r < 4; ++r) {
        float m = va[r].x; int i0 = 4 * l;
        if (va[r].y > m) { m = va[r].y; i0 = 4 * l + 1; }
        if (va[r].z > m) { m = va[r].z; i0 = 4 * l + 2; }
        if (va[r].w > m) { m = va[r].w; i0 = 4 * l + 3; }
        if (vb[r].x > m) { m = vb[r].x; i0 = 256 + 4 * l; }
        if (vb[r].y > m) { m = vb[r].y; i0 = 256 + 4 * l + 1; }
        if (vb[r].z > m) { m = vb[r].z; i0 = 256 + 4 * l + 2; }
        if (vb[r].w > m) { m = vb[r].w; i0 = 256 + 4 * l + 3; }
        mv[r] = m; mi[r] = i0;
    }

    // 4 interleaved butterflies: (max, min-index-on-tie) is assoc+comm
    #pragma unroll
    for (int off = 1; off < 64; off <<= 1) {
        #pragma unroll
        for (int r = 0; r < 4; ++r) {
            float ov = __shfl_xor(mv[r], off, 64);
            int   oi = __shfl_xor(mi[r], off, 64);
            if (ov > mv[r] || (ov == mv[r] && oi < mi[r])) { mv[r] = ov; mi[r] = oi; }
        }
    }

    // exp sums (mv[r] is now the true row max)
    float ss[4];
    #pragma unroll
    for (int r = 0; r < 4; ++r) {
        ss[r] = __expf(va[r].x - mv[r]) + __expf(va[r].y - mv[r])
              + __expf(va[r].z - mv[r]) + __expf(va[r].w - mv[r])
              + __expf(vb[r].x - mv[r]) + __expf(vb[r].y - mv[r])
              + __expf(vb[r].z - mv[r]) + __expf(vb[r].w - mv[r]);
    }
    #pragma unroll
    for (int off = 1; off < 64; off <<= 1) {
        #pragma unroll
        for (int r = 0; r < 4; ++r) ss[r] += __shfl_xor(ss[r], off, 64);
    }

    float l0 = mv[0] + __logf(ss[0]);
    float l1 = mv[1] + __logf(ss[1]);
    float l2 = mv[2] + __logf(ss[2]);
    float l3 = mv[3] + __logf(ss[3]);

    if (l == 0) {
        *(float4*)(lse + rowBase) = make_float4(l0, l1, l2, l3);   // 16B aligned
        *(int4*)(am + rowBase) = make_int4(mi[0], mi[1], mi[2], mi[3]);
    }

    // column sums: lane l owns cols {4l..4l+3, 256+4l..256+4l+3} of its 4 rows
    float cs0 = va[0].x + va[1].x + va[2].x + va[3].x;
    float cs1 = va[0].y + va[1].y + va[2].y + va[3].y;
    float cs2 = va[0].z + va[1].z + va[2].z + va[3].z;
    float cs3 = va[0].w + va[1].w + va[2].w + va[3].w;
    float cs4 = vb[0].x + vb[1].x + vb[2].x + vb[3].x;
    float cs5 = vb[0].y + vb[1].y + vb[2].y + vb[3].y;
    float cs6 = vb[0].z + vb[1].z + vb[2].z + vb[3].z;
    float cs7 = vb[0].w + vb[1].w + vb[2].w + vb[3].w;

    __shared__ float lds[4][PC];   // 8 KB
    lds[w][4 * l + 0] = cs0; lds[w][4 * l + 1] = cs1;
    lds[w][4 * l + 2] = cs2; lds[w][4 * l + 3] = cs3;
    lds[w][256 + 4 * l + 0] = cs4; lds[w][256 + 4 * l + 1] = cs5;
    lds[w][256 + 4 * l + 2] = cs6; lds[w][256 + 4 * l + 3] = cs7;
    __syncthreads();
    for (int c = t; c < PC; c += 256) {
        float s = lds[0][c] + lds[1][c] + lds[2][c] + lds[3][c];
        atomicAdd(&colsum[(b << 9) + c], s);   // all 4 waves share b
    }
}

// ---------------------------------------------------------------------------
// K_TAIL (R3): one block (1024 threads) per batch. Same pass-1 / histogram /
// scan / scatter as R1. Eval split into 3 phases to kill the serial per-class
// gather chain (was: max-k/2 ~ 10 dependent rounds x ~700cy of L3 latency):
//   E1: mode per class (LDS-only O(k^2), unchanged) -> smode[]
//   E2: element-parallel — each thread issues its 4 independent
//       pred[s, mode[tgt[s]]] gathers in ONE latency round, writes
//       tval[s] = lse[s] - pred[s,m] to LDS
//   E3: per-class sum over tval (fast LDS reads, same bucket order)
// ---------------------------------------------------------------------------
__global__ __launch_bounds__(1024) void k_tail(const float* __restrict__ pred,
                                               const int* __restrict__ target,
                                               const int* __restrict__ am,
                                               const float* __restrict__ lse,
                                               const float* __restrict__ colsum,
                                               float* __restrict__ acc,
                                               int* __restrict__ done,
                                               float* __restrict__ out) {
    __shared__ float ldsLse[PS];   // 16 KB
    __shared__ int   sbucket[PS];  // 16 KB: s | am<<12
    __shared__ float tval[PS];     // 16 KB: lse[s] - pred[s, mode[tgt[s]]]
    __shared__ int   cnt[PC];      // 2 KB
    __shared__ int   offsA[PC];    // 2 KB
    __shared__ int   cur[PC];      // 2 KB
    __shared__ int   smode[PC];    // 2 KB
    __shared__ float redL[16];
    __shared__ int   redS[8];
    __shared__ float redv[16], redk[16];

    const int b = blockIdx.x, t = threadIdx.x, w = t >> 6, l = t & 63;
    if (t < PC) cnt[t] = 0;
    __syncthreads();

    // pass 1: 4 consecutive elements per thread, fully vectorized
    const int4*   tg4p = (const int4*)(target + (b << 12));
    const int4*   am4p = (const int4*)(am + (b << 12));
    const float4* ls4p = (const float4*)(lse + (b << 12));
    int4 tg4 = tg4p[t];
    int4 am4 = am4p[t];
    float4 ls4 = ls4p[t];
    ((float4*)ldsLse)[t] = ls4;
    atomicAdd(&cnt[tg4.x], 1);
    atomicAdd(&cnt[tg4.y], 1);
    atomicAdd(&cnt[tg4.z], 1);
    atomicAdd(&cnt[tg4.w], 1);
    float lacc = ls4.x + ls4.y + ls4.z + ls4.w;
    #pragma unroll
    for (int off = 1; off < 64; off <<= 1) lacc += __shfl_xor(lacc, off, 64);
    if (l == 0) redL[w] = lacc;
    __syncthreads();                       // cnt, ldsLse, redL ready
    float Ls = 0.0f;
    #pragma unroll
    for (int j = 0; j < 16; ++j) Ls += redL[j];

    // exclusive scan over 512 classes: threads 0..511 (waves 0..7), shfl scan
    int x = 0, incl = 0;
    if (t < PC) {
        x = cnt[t];
        incl = x;
        #pragma unroll
        for (int off = 1; off < 64; off <<= 1) {
            int v = __shfl_up(incl, off, 64);
            if (l >= off) incl += v;
        }
        if (l == 63) redS[w] = incl;
    }
    __syncthreads();
    if (t < PC) {
        int woff = 0;
        #pragma unroll
        for (int j = 0; j < 8; ++j) woff += (j < w) ? redS[j] : 0;
        int excl = incl + woff - x;
        offsA[t] = excl;
        cur[t] = excl;
    }
    __syncthreads();

    // scatter from registers (elements 4t..4t+3)
    {
        int pos;
        pos = atomicAdd(&cur[tg4.x], 1); sbucket[pos] = (4 * t + 0) | (am4.x << 12);
        pos = atomicAdd(&cur[tg4.y], 1); sbucket[pos] = (4 * t + 1) | (am4.y << 12);
        pos = atomicAdd(&cur[tg4.z], 1); sbucket[pos] = (4 * t + 2) | (am4.z << 12);
        pos = atomicAdd(&cur[tg4.w], 1); sbucket[pos] = (4 * t + 3) | (am4.w << 12);
    }
    __syncthreads();

    // E1: mode per class (LDS-only; tie -> smallest class, matches argmax)
    if (t < PC && x > 0) {
        int k = x, start = offsA[t];
        int bc = 0, bvv = 0;
        for (int i = 0; i < k; ++i) {
            int v = sbucket[start + i] >> 12;
            int c = 0;
            for (int j = 0; j < k; ++j) c += ((sbucket[start + j] >> 12) == v) ? 1 : 0;
            if (c > bc || (c == bc && v < bvv)) { bc = c; bvv = v; }
        }
        smode[t] = bvv;
    }
    __syncthreads();                       // smode ready

    // E2: element-parallel gathers — 4 independent loads per thread, 1 round
    {
        const float* pbase = pred + ((size_t)(b << 12) + 4 * (size_t)t) * PC;
        int m0 = smode[tg4.x], m1 = smode[tg4.y], m2 = smode[tg4.z], m3 = smode[tg4.w];
        float p0 = pbase[m0];
        float p1 = pbase[PC + m1];
        float p2 = pbase[2 * PC + m2];
        float p3 = pbase[3 * PC + m3];
        tval[4 * t + 0] = ls4.x - p0;
        tval[4 * t + 1] = ls4.y - p1;
        tval[4 * t + 2] = ls4.z - p2;
        tval[4 * t + 3] = ls4.w - p3;
    }
    __syncthreads();                       // tval ready

    // E3: per-class sum over tval (LDS, bucket order) + formula
    float val = 0.0f; int keep = 0;
    if (t < PC && x > 0) {
        int k = x, start = offsA[t];
        int m = smode[t];
        float e0 = 0.0f, e1 = 0.0f;
        int i = 0;
        for (; i + 1 < k; i += 2) {
            int s0 = sbucket[start + i] & (PS - 1);
            int s1 = sbucket[start + i + 1] & (PS - 1);
            e0 += tval[s0];
            e1 += tval[s1];
        }
        if (i < k) e0 += tval[sbucket[start + i] & (PS - 1)];
        float eq_sum = e0 + e1;
        float ne_sum = (Ls - colsum[(b << 9) + m]) - eq_sum;
        float nf = (float)k;
        float eq_loss = eq_sum / fmaxf(nf, 1.0f);
        float ne_mean = ne_sum / fmaxf((float)PS - nf, 1.0f);
        float ne_loss = 1.0f / ((ne_mean != 0.0f) ? ne_mean : 1.0f);
        val = 0.5f * eq_loss + 0.5f * ne_loss;
        keep = (val != 0.0f) ? 1 : 0;
    }

    float vs = keep ? val : 0.0f;
    float ks = (float)keep;
    #pragma unroll
    for (int off = 1; off < 64; off <<= 1) {
        vs += __shfl_xor(vs, off, 64);
        ks += __shfl_xor(ks, off, 64);
    }
    if (l == 0) { redv[w] = vs; redk[w] = ks; }
    __syncthreads();
    if (t == 0) {
        float sv = 0.0f, sk = 0.0f;
        #pragma unroll
        for (int j = 0; j < 16; ++j) { sv += redv[j]; sk += redk[j]; }
        atomicAdd(&acc[0], sv);
        atomicAdd(&acc[1], sk);
        __threadfence();
        int d = atomicAdd(done, 1);
        if (d == PB - 1) {                 // last batch-block finalizes
            __threadfence();
            float a0 = atomicAdd(&acc[0], 0.0f);
            float a1 = atomicAdd(&acc[1], 0.0f);
            out[0] = a0 / fmaxf(a1, 1.0f);
        }
    }
}

extern "C" void kernel_launch(void* const* d_in, const int* in_sizes, int n_in,
                              void* d_out, int out_size, void* d_ws, size_t ws_size,
                              hipStream_t stream) {
    const float* pred = (const float*)d_in[0];   // (B,S,C) f32
    const int* target = (const int*)d_in[1];     // (B,S) int
    float* out = (float*)d_out;

    char* w = (char*)d_ws;
    int*   am     = (int*)(w + 0);          // B*S ints   = 256 KiB
    float* lse    = (float*)(w + 262144);   // B*S floats = 256 KiB
    float* colsum = (float*)(w + 524288);   // B*C floats =  32 KiB  <- memset 0
    float* acc    = (float*)(w + 557056);   // 2 floats             <- memset 0
    int*   done   = (int*)(w + 557064);     // 1 int                <- memset 0

    (void)hipMemsetAsync(w + 524288, 0, 32768 + 12, stream);
    k1_rows<<<(PB * PS) / 16, 256, 0, stream>>>(pred, am, lse, colsum);
    k_tail<<<PB, 1024, 0, stream>>>(pred, target, am, lse, colsum, acc, done, out);
}

// Round 5
// 217.870 us; speedup vs baseline: 1.0415x; 1.0298x over previous
//
#include <hip/hip_runtime.h>
#include <cstdint>
#include <cstddef>

// Problem constants (from reference): B=16, S=4096, C=512, A=0.5
#define PB 16
#define PS 4096
#define PC 512

// ---------------------------------------------------------------------------
// K1: register-direct streaming pass (R5 structure — measured fastest:
// 218.7/220.0 µs total). 4096 blocks x 256 thr; each wave owns 4 rows,
// issues all 8 float4 loads up front. 4 interleaved butterfly chains (ILP=4).
// Measured-null/negative alternatives (do NOT revisit):
//   R2: 64-row blocks + de-atomicized colsum  -> +6.9 µs (occupancy loss;
//       atomics proven cheap)
//   R3: three-phase tail w/ parallel gather    -> +4.4 µs
//   R8: nontemporal loads                      -> +2.5 µs (pred is L3-hot)
//   R6: __threadfence publication              -> +489 µs (L2 writeback)
//   R4: min-waves launch bound                 -> VGPR squeeze serializes loads
// ---------------------------------------------------------------------------
__global__ __launch_bounds__(256) void k1_rows(const float* __restrict__ pred,
                                               int* __restrict__ am,
                                               float* __restrict__ lse,
                                               float* __restrict__ colsum) {
    const int t = threadIdx.x, w = t >> 6, l = t & 63;
    const int rowBase = blockIdx.x * 16 + w * 4;   // 4 consecutive rows per wave
    const int b = rowBase >> 12;                   // PS = 4096
    const float* base = pred + (size_t)rowBase * PC + 4 * l;

    float4 va[4], vb[4];
    #pragma unroll
    for (int r = 0; r < 4; ++r) {
        va[r] = *(const float4*)(base + r * PC);
        vb[r] = *(const float4*)(base + r * PC + 256);
    }

    // lane-local argmax over 8 elements per row (earliest index wins: strict >)
    float mv[4]; int mi[4];
    #pragma unroll
    for (int r = 0; r < 4; ++r) {
        float m = va[r].x; int i0 = 4 * l;
        if (va[r].y > m) { m = va[r].y; i0 = 4 * l + 1; }
        if (va[r].z > m) { m = va[r].z; i0 = 4 * l + 2; }
        if (va[r].w > m) { m = va[r].w; i0 = 4 * l + 3; }
        if (vb[r].x > m) { m = vb[r].x; i0 = 256 + 4 * l; }
        if (vb[r].y > m) { m = vb[r].y; i0 = 256 + 4 * l + 1; }
        if (vb[r].z > m) { m = vb[r].z; i0 = 256 + 4 * l + 2; }
        if (vb[r].w > m) { m = vb[r].w; i0 = 256 + 4 * l + 3; }
        mv[r] = m; mi[r] = i0;
    }

    // 4 interleaved butterflies: (max, min-index-on-tie) is assoc+comm
    #pragma unroll
    for (int off = 1; off < 64; off <<= 1) {
        #pragma unroll
        for (int r = 0; r < 4; ++r) {
            float ov = __shfl_xor(mv[r], off, 64);
            int   oi = __shfl_xor(mi[r], off, 64);
            if (ov > mv[r] || (ov == mv[r] && oi < mi[r])) { mv[r] = ov; mi[r] = oi; }
        }
    }

    // exp sums (mv[r] is now the true row max)
    float ss[4];
    #pragma unroll
    for (int r = 0; r < 4; ++r) {
        ss[r] = __expf(va[r].x - mv[r]) + __expf(va[r].y - mv[r])
              + __expf(va[r].z - mv[r]) + __expf(va[r].w - mv[r])
              + __expf(vb[r].x - mv[r]) + __expf(vb[r].y - mv[r])
              + __expf(vb[r].z - mv[r]) + __expf(vb[r].w - mv[r]);
    }
    #pragma unroll
    for (int off = 1; off < 64; off <<= 1) {
        #pragma unroll
        for (int r = 0; r < 4; ++r) ss[r] += __shfl_xor(ss[r], off, 64);
    }

    float l0 = mv[0] + __logf(ss[0]);
    float l1 = mv[1] + __logf(ss[1]);
    float l2 = mv[2] + __logf(ss[2]);
    float l3 = mv[3] + __logf(ss[3]);

    if (l == 0) {
        *(float4*)(lse + rowBase) = make_float4(l0, l1, l2, l3);   // 16B aligned
        *(int4*)(am + rowBase) = make_int4(mi[0], mi[1], mi[2], mi[3]);
    }

    // column sums: lane l owns cols {4l..4l+3, 256+4l..256+4l+3} of its 4 rows
    float cs0 = va[0].x + va[1].x + va[2].x + va[3].x;
    float cs1 = va[0].y + va[1].y + va[2].y + va[3].y;
    float cs2 = va[0].z + va[1].z + va[2].z + va[3].z;
    float cs3 = va[0].w + va[1].w + va[2].w + va[3].w;
    float cs4 = vb[0].x + vb[1].x + vb[2].x + vb[3].x;
    float cs5 = vb[0].y + vb[1].y + vb[2].y + vb[3].y;
    float cs6 = vb[0].z + vb[1].z + vb[2].z + vb[3].z;
    float cs7 = vb[0].w + vb[1].w + vb[2].w + vb[3].w;

    __shared__ float lds[4][PC];   // 8 KB
    lds[w][4 * l + 0] = cs0; lds[w][4 * l + 1] = cs1;
    lds[w][4 * l + 2] = cs2; lds[w][4 * l + 3] = cs3;
    lds[w][256 + 4 * l + 0] = cs4; lds[w][256 + 4 * l + 1] = cs5;
    lds[w][256 + 4 * l + 2] = cs6; lds[w][256 + 4 * l + 3] = cs7;
    __syncthreads();
    for (int c = t; c < PC; c += 256) {
        float s = lds[0][c] + lds[1][c] + lds[2][c] + lds[3][c];
        atomicAdd(&colsum[(b << 9) + c], s);   // all 4 waves share b
    }
}

// ---------------------------------------------------------------------------
// K_TAIL: one block (1024 threads) per batch. Vectorized pass-1 into
// registers (4 elems/thread via int4/float4), LDS histogram, shfl wave-scan
// (2 barriers), register scatter, per-class mode/eq/ne/val, block reduce ->
// acc atomics, done-protocol finalize. (R3's 3-phase parallel-gather eval
// measured +4.4 µs — serial chain is short, avg class size ~8.)
// ---------------------------------------------------------------------------
__global__ __launch_bounds__(1024) void k_tail(const float* __restrict__ pred,
                                               const int* __restrict__ target,
                                               const int* __restrict__ am,
                                               const float* __restrict__ lse,
                                               const float* __restrict__ colsum,
                                               float* __restrict__ acc,
                                               int* __restrict__ done,
                                               float* __restrict__ out) {
    __shared__ float ldsLse[PS];   // 16 KB
    __shared__ int   sbucket[PS];  // 16 KB: s | am<<12
    __shared__ int   cnt[PC];      // 2 KB
    __shared__ int   offsA[PC];    // 2 KB
    __shared__ int   cur[PC];      // 2 KB
    __shared__ float redL[16];
    __shared__ int   redS[8];
    __shared__ float redv[16], redk[16];

    const int b = blockIdx.x, t = threadIdx.x, w = t >> 6, l = t & 63;
    if (t < PC) cnt[t] = 0;
    __syncthreads();

    // pass 1: 4 consecutive elements per thread, fully vectorized
    const int4*   tg4p = (const int4*)(target + (b << 12));
    const int4*   am4p = (const int4*)(am + (b << 12));
    const float4* ls4p = (const float4*)(lse + (b << 12));
    int4 tg4 = tg4p[t];
    int4 am4 = am4p[t];
    float4 ls4 = ls4p[t];
    ((float4*)ldsLse)[t] = ls4;
    atomicAdd(&cnt[tg4.x], 1);
    atomicAdd(&cnt[tg4.y], 1);
    atomicAdd(&cnt[tg4.z], 1);
    atomicAdd(&cnt[tg4.w], 1);
    float lacc = ls4.x + ls4.y + ls4.z + ls4.w;
    #pragma unroll
    for (int off = 1; off < 64; off <<= 1) lacc += __shfl_xor(lacc, off, 64);
    if (l == 0) redL[w] = lacc;
    __syncthreads();                       // cnt, ldsLse, redL ready
    float Ls = 0.0f;
    #pragma unroll
    for (int j = 0; j < 16; ++j) Ls += redL[j];

    // exclusive scan over 512 classes: threads 0..511 (waves 0..7), shfl scan
    int x = 0, incl = 0;
    if (t < PC) {
        x = cnt[t];
        incl = x;
        #pragma unroll
        for (int off = 1; off < 64; off <<= 1) {
            int v = __shfl_up(incl, off, 64);
            if (l >= off) incl += v;
        }
        if (l == 63) redS[w] = incl;
    }
    __syncthreads();
    if (t < PC) {
        int woff = 0;
        #pragma unroll
        for (int j = 0; j < 8; ++j) woff += (j < w) ? redS[j] : 0;
        int excl = incl + woff - x;
        offsA[t] = excl;
        cur[t] = excl;
    }
    __syncthreads();

    // scatter from registers (elements 4t..4t+3)
    {
        int pos;
        pos = atomicAdd(&cur[tg4.x], 1); sbucket[pos] = (4 * t + 0) | (am4.x << 12);
        pos = atomicAdd(&cur[tg4.y], 1); sbucket[pos] = (4 * t + 1) | (am4.y << 12);
        pos = atomicAdd(&cur[tg4.z], 1); sbucket[pos] = (4 * t + 2) | (am4.z << 12);
        pos = atomicAdd(&cur[tg4.w], 1); sbucket[pos] = (4 * t + 3) | (am4.w << 12);
    }
    __syncthreads();

    // per-class eval: thread t < 512 owns class t
    float val = 0.0f; int keep = 0;
    if (t < PC && x > 0) {
        int k = x, start = offsA[t];
        int bc = 0, bvv = 0;               // mode; tie -> smallest class
        for (int i = 0; i < k; ++i) {
            int v = sbucket[start + i] >> 12;
            int c = 0;
            for (int j = 0; j < k; ++j) c += ((sbucket[start + j] >> 12) == v) ? 1 : 0;
            if (c > bc || (c == bc && v < bvv)) { bc = c; bvv = v; }
        }
        int m = bvv;
        float lseSum = 0.0f, ep0 = 0.0f, ep1 = 0.0f;
        const float* pb = pred + (size_t)(b << 12) * PC + m;
        int i = 0;
        for (; i + 1 < k; i += 2) {        // 2-way unroll: 2 loads in flight
            int s0 = sbucket[start + i] & (PS - 1);
            int s1 = sbucket[start + i + 1] & (PS - 1);
            lseSum += ldsLse[s0] + ldsLse[s1];
            ep0 += pb[(size_t)s0 * PC];
            ep1 += pb[(size_t)s1 * PC];
        }
        if (i < k) {
            int s0 = sbucket[start + i] & (PS - 1);
            lseSum += ldsLse[s0];
            ep0 += pb[(size_t)s0 * PC];
        }
        float eq_sum = lseSum - (ep0 + ep1);
        float ne_sum = (Ls - colsum[(b << 9) + m]) - eq_sum;
        float nf = (float)k;
        float eq_loss = eq_sum / fmaxf(nf, 1.0f);
        float ne_mean = ne_sum / fmaxf((float)PS - nf, 1.0f);
        float ne_loss = 1.0f / ((ne_mean != 0.0f) ? ne_mean : 1.0f);
        val = 0.5f * eq_loss + 0.5f * ne_loss;
        keep = (val != 0.0f) ? 1 : 0;
    }

    float vs = keep ? val : 0.0f;
    float ks = (float)keep;
    #pragma unroll
    for (int off = 1; off < 64; off <<= 1) {
        vs += __shfl_xor(vs, off, 64);
        ks += __shfl_xor(ks, off, 64);
    }
    if (l == 0) { redv[w] = vs; redk[w] = ks; }
    __syncthreads();
    if (t == 0) {
        float sv = 0.0f, sk = 0.0f;
        #pragma unroll
        for (int j = 0; j < 16; ++j) { sv += redv[j]; sk += redk[j]; }
        atomicAdd(&acc[0], sv);
        atomicAdd(&acc[1], sk);
        __threadfence();
        int d = atomicAdd(done, 1);
        if (d == PB - 1) {                 // last batch-block finalizes
            __threadfence();
            float a0 = atomicAdd(&acc[0], 0.0f);
            float a1 = atomicAdd(&acc[1], 0.0f);
            out[0] = a0 / fmaxf(a1, 1.0f);
        }
    }
}

extern "C" void kernel_launch(void* const* d_in, const int* in_sizes, int n_in,
                              void* d_out, int out_size, void* d_ws, size_t ws_size,
                              hipStream_t stream) {
    const float* pred = (const float*)d_in[0];   // (B,S,C) f32
    const int* target = (const int*)d_in[1];     // (B,S) int
    float* out = (float*)d_out;

    char* w = (char*)d_ws;
    int*   am     = (int*)(w + 0);          // B*S ints   = 256 KiB
    float* lse    = (float*)(w + 262144);   // B*S floats = 256 KiB
    float* colsum = (float*)(w + 524288);   // B*C floats =  32 KiB  <- memset 0
    float* acc    = (float*)(w + 557056);   // 2 floats             <- memset 0
    int*   done   = (int*)(w + 557064);     // 1 int                <- memset 0

    (void)hipMemsetAsync(w + 524288, 0, 32768 + 12, stream);
    k1_rows<<<(PB * PS) / 16, 256, 0, stream>>>(pred, am, lse, colsum);
    k_tail<<<PB, 1024, 0, stream>>>(pred, target, am, lse, colsum, acc, done, out);
}